// Round 4
// baseline (166.708 us; speedup 1.0000x reference)
//
#include <hip/hip_runtime.h>
#include <math.h>

#define BT 256   // 4 waves; each wave = TWO 32-element tiles x TWO passes (128 elems)

typedef _Float16 half2v __attribute__((ext_vector_type(2)));
typedef __fp16   fp16x2 __attribute__((ext_vector_type(2)));
typedef _Float16 half8  __attribute__((ext_vector_type(8)));
typedef float    f32x16 __attribute__((ext_vector_type(16)));

union U4H8 { unsigned int u[4]; half8 h; };

__device__ __forceinline__ half2v u2h(unsigned int u){
  union { unsigned int u; half2v h; } c; c.u = u; return c.h;
}
__device__ __forceinline__ unsigned int h2u(half2v h){
  union { unsigned int u; half2v h; } c; c.h = h; return c.u;
}
__device__ __forceinline__ half2v pkrtz(float a, float b){
  union { fp16x2 f; half2v h; } c;
  c.f = __builtin_amdgcn_cvt_pkrtz(a, b);
  return c.h;
}
__device__ __forceinline__ float fdot2(half2v a, half2v b, float c){
  return __builtin_amdgcn_fdot2(a, b, c, false);
}
__device__ __forceinline__ float frcp(float x){ return __builtin_amdgcn_rcpf(x); }

__device__ __forceinline__ unsigned int pk_rne(float a, float b){
  half2v h; h.x = (_Float16)a; h.y = (_Float16)b; return h2u(h);
}

// Cross-half (lane ^ 32) data movement on the VALU pipe (no DS / lgkm wait).
#if __has_builtin(__builtin_amdgcn_permlane32_swap)
#define HAVE_PLSWAP 1
#endif

__device__ __forceinline__ float red_sum32(float v){
#ifdef HAVE_PLSWAP
  union { float f; unsigned u; } c; c.f = v;
  auto r = __builtin_amdgcn_permlane32_swap(c.u, c.u, false, false);
  union { unsigned u; float f; } a, b; a.u = r[0]; b.u = r[1];
  return a.f + b.f;
#else
  return v + __shfl_xor(v, 32);
#endif
}
// lanes<32 receive v[l+32] (upper lanes get own value back)
__device__ __forceinline__ float upper_to_lower(float v){
#ifdef HAVE_PLSWAP
  union { float f; unsigned u; } c; c.f = v;
  auto r = __builtin_amdgcn_permlane32_swap(c.u, c.u, false, false);
  union { unsigned u; float f; } b; b.u = r[1];
  return b.f;
#else
  return __shfl_xor(v, 32);
#endif
}

// packed-f16 gelu: gelu(x) = x*S, S = clamp(0.5 + x*q(x^2), 0, 1);
// q deg-4 fit on t in [0,4]; |gelu err| <= 2.3e-4 on |x|<=2, correct asymptote beyond.
__device__ __forceinline__ half2v gelu_pk(half2v x){
  const _Float16 a0 = (_Float16)0.3989423f,  a1 = (_Float16)-0.0663157f,
                 a2 = (_Float16)0.0096298f,  a3 = (_Float16)-0.00095967f,
                 a4 = (_Float16)0.000048f,   hp = (_Float16)0.5f,
                 hn = (_Float16)-0.5f;
  const half2v A0={a0,a0}, A1={a1,a1}, A2={a2,a2}, A3={a3,a3}, A4={a4,a4};
  const half2v HP={hp,hp}, HN={hn,hn};
  half2v t = x*x;
  half2v q = A4*t + A3;
  q = q*t + A2;
  q = q*t + A1;
  q = q*t + A0;
  half2v u = x*q;
#if __has_builtin(__builtin_elementwise_min)
  u = __builtin_elementwise_max(u, HN);
  u = __builtin_elementwise_min(u, HP);
#else
  u.x = u.x > hp ? hp : (u.x < hn ? hn : u.x);
  u.y = u.y > hp ? hp : (u.y < hn ? hn : u.y);
#endif
  return x*(u + HP);
}

// packed-f16 tanh: clamp +-2, x*P(x^2), deg-5 fit (|err| ~5e-4 incl f16 rounding).
__device__ __forceinline__ half2v tanh_pk(half2v x){
  const _Float16 c0=(_Float16)0.999716f,  c1=(_Float16)-0.328107f,
                 c2=(_Float16)0.116352f,  c3=(_Float16)-0.031255f,
                 c4=(_Float16)0.005038f,  c5=(_Float16)-0.000348f,
                 tp=(_Float16)2.0f,       tn=(_Float16)-2.0f;
  const half2v C0={c0,c0},C1={c1,c1},C2={c2,c2},C3={c3,c3},C4={c4,c4},C5={c5,c5};
  const half2v TP={tp,tp}, TN={tn,tn};
#if __has_builtin(__builtin_elementwise_min)
  x = __builtin_elementwise_max(x, TN);
  x = __builtin_elementwise_min(x, TP);
#else
  x.x = x.x > tp ? tp : (x.x < tn ? tn : x.x);
  x.y = x.y > tp ? tp : (x.y < tn ? tn : x.y);
#endif
  half2v t = x*x;
  half2v p = C5*t + C4;
  p = p*t + C3;
  p = p*t + C2;
  p = p*t + C1;
  p = p*t + C0;
  return x*p;
}

// ---------------- ws layout (u32 words) ----------------
// sigma-permuted columns (pair j of a row = original cols c0,c0+1,
// c0 = 16*(j>>3) + 8*((j>>1)&1) + 4*((j>>2)&1) + 2*(j&1)) so the packed C/D
// pair array of the previous MFMA is directly the next B-fragment.
//  [0,512)     A_pk   : iss * Wq^T Wk            [32][16] pairs, perm cols
//  [512,1024)  M_pk   : M = W_ih*OP*WV           perm cols
//  [1024,1536) W_pk   : whh                      perm cols
//  [1536,2048) D_pk   : rows 0-4 = decw, else 0  perm cols
//  [2048,2304) emb_pk : [32][8] pairs; k<5 = embw, k=5 = embb (bias slot), else 0
//  [2304,2320) wv_pk  : iss * Wk^T bq, [grp][8] C/D row-pair order
//  [2320,2352) bM_f   : f32, bM = W_ih*(OP bv + opb) + b_ih + b_hh (natural)
//  [2352,2355) decb_pk: (b0,b1),(b2,b3),(b4,0)
//  [2355,2364) out_pk : row r: (w0,w1),(w2,w3),(w4,0)
__global__ void prep_kernel(const float* __restrict__ inw, const float* __restrict__ inb,
                            const float* __restrict__ opw, const float* __restrict__ opb,
                            const float* __restrict__ wih, const float* __restrict__ bih,
                            const float* __restrict__ bhh, const float* __restrict__ whh,
                            const float* __restrict__ decw, const float* __restrict__ embw,
                            const float* __restrict__ embb,
                            const float* __restrict__ decb, const float* __restrict__ outw,
                            unsigned int* __restrict__ wsu){
  __shared__ float sQ[1024], sK[1024], sV[1024], sOP[1024], sWI[1024];
  __shared__ float sA[1024], sP[1024], sM[1024], sT[32], sWV[32];
  const float ISS = 0.17677669529663689f;   // 1/sqrt(32)
  int t = threadIdx.x;
  sQ[t]  = inw[t];
  sK[t]  = inw[1024 + t];
  sV[t]  = inw[2048 + t];
  sOP[t] = opw[t];
  sWI[t] = wih[t];
  __syncthreads();
  int tx = t & 31, ty = t >> 5;
  float accA = 0.f, accP = 0.f;
  #pragma unroll
  for (int m = 0; m < 32; m++){
    accA += sQ[m*32 + ty] * sK[m*32 + tx];    // Wq[m,ty]*Wk[m,tx]
    accP += sOP[ty*32 + m] * sV[m*32 + tx];   // OP[ty,m]*WV[m,tx]
  }
  sA[ty*32 + tx] = accA;
  sP[ty*32 + tx] = accP;
  if (ty == 0){
    float aw = 0.f;
    #pragma unroll
    for (int m = 0; m < 32; m++) aw += inb[m] * sK[m*32 + tx];   // bq[m]*Wk[m,tx]
    sWV[tx] = aw;
  }
  if (ty == 1){
    float at = opb[tx];
    #pragma unroll
    for (int m = 0; m < 32; m++) at += sOP[tx*32 + m] * inb[64 + m];  // OP[tx,m]*bv[m]
    sT[tx] = at;
  }
  __syncthreads();
  float accM = 0.f;
  #pragma unroll
  for (int m = 0; m < 32; m++) accM += sWI[ty*32 + m] * sP[m*32 + tx];
  sM[ty*32 + tx] = accM;
  if (ty == 2){
    float ab = bih[tx] + bhh[tx];
    #pragma unroll
    for (int m = 0; m < 32; m++) ab += sWI[tx*32 + m] * sT[m];
    ((float*)wsu)[2320 + tx] = ab;
  }
  __syncthreads();
  if (t < 512){
    int r = t >> 4, j = t & 15;
    int c0 = 16*(j>>3) + 8*((j>>1)&1) + 4*((j>>2)&1) + 2*(j&1);   // sigma-perm
    wsu[t]        = pk_rne(ISS*sA[r*32+c0], ISS*sA[r*32+c0+1]);
    wsu[512 + t]  = pk_rne(sM[r*32+c0],  sM[r*32+c0+1]);
    wsu[1024 + t] = pk_rne(whh[r*32+c0], whh[r*32+c0+1]);
    wsu[1536 + t] = (r < 5) ? pk_rne(decw[r*32+c0], decw[r*32+c0+1]) : 0u;
  } else if (t < 768){                     // emb_pk: [32][8] pairs; k5 = embb
    int q = t - 512, j2 = q >> 3, cc = (q & 7)*2;
    float a = (cc   < 5) ? embw[j2*5+cc]   : 0.f;
    float b = (cc+1 < 5) ? embw[j2*5+cc+1] : ((cc+1 == 5) ? embb[j2] : 0.f);
    wsu[2048 + q] = pk_rne(a, b);
  } else if (t < 784){                     // wv_pk in C/D row-pair order, iss-scaled
    int q = t - 768, gg = q >> 3, j = q & 7;
    int r0 = 2*(j&1) + 8*(j>>1) + 4*gg;
    wsu[2304 + q] = pk_rne(ISS*sWV[r0], ISS*sWV[r0+1]);
  } else if (t < 787){                     // decb_pk
    int i = t - 784, c = 2*i;
    float a = decb[c];
    float b = (c+1 < 5) ? decb[c+1] : 0.f;
    wsu[2352 + i] = pk_rne(a, b);
  } else if (t < 796){                     // out_pk: 3 rows x 3 pairs
    int q = t - 787;
    int r = (q >= 6) ? 2 : ((q >= 3) ? 1 : 0);
    int p = q - r*3, c = 2*p;
    float a = outw[r*5 + c];
    float b = (c+1 < 5) ? outw[r*5 + c + 1] : 0.f;
    wsu[2355 + q] = pk_rne(a, b);
  }
}

__device__ __forceinline__ half8 ldfrag(const unsigned int* __restrict__ p){
  U4H8 t; t.u[0]=p[0]; t.u[1]=p[1]; t.u[2]=p[2]; t.u[3]=p[3]; return t.h;
}
__device__ __forceinline__ half8 h8of(const unsigned int* q){
  U4H8 t; t.u[0]=q[0]; t.u[1]=q[1]; t.u[2]=q[2]; t.u[3]=q[3]; return t.h;
}

// 16 f32 bias values for this lane's C-frag rows via 4x float4
__device__ __forceinline__ f32x16 ldbias(const float* __restrict__ p, int grp){
  const float4* b = (const float4*)(p + 4*grp);
  float4 q0 = b[0], q1 = b[2], q2 = b[4], q3 = b[6];
  f32x16 c;
  c[0]=q0.x; c[1]=q0.y; c[2]=q0.z; c[3]=q0.w;
  c[4]=q1.x; c[5]=q1.y; c[6]=q1.z; c[7]=q1.w;
  c[8]=q2.x; c[9]=q2.y; c[10]=q2.z; c[11]=q2.w;
  c[12]=q3.x; c[13]=q3.y; c[14]=q3.z; c[15]=q3.w;
  return c;
}

__global__ __launch_bounds__(BT, 4) void fused_kernel(
    const float* __restrict__ x,
    const unsigned int* __restrict__ wsu,
    const float* __restrict__ outb,
    float* __restrict__ y, long long B)
{
  int tid  = threadIdx.x;
  int lane = tid & 63;
  int col  = lane & 31;
  bool g   = (lane >> 5) != 0;
  int grp  = g ? 1 : 0;
  // each wave owns 128 contiguous elements (two passes of 64)
  long long eW = ((long long)blockIdx.x*(BT/64) + (tid>>6)) * 128;
  if (eW >= B) return;

  const unsigned int* pA = wsu;
  const unsigned int* pM = wsu + 512;
  const unsigned int* pW = wsu + 1024;
  const unsigned int* pD = wsu + 1536;
  const unsigned int* pE = wsu + 2048;
  const unsigned int* pwv = wsu + 2304;
  const float* bMf = (const float*)(wsu + 2320);
  const unsigned int* pdb  = wsu + 2352;
  const unsigned int* pout = wsu + 2355;

  half8 embA = ldfrag(pE + col*8  + grp*4);
  half8 A1   = ldfrag(pA + col*16 + grp*4), A2 = ldfrag(pA + col*16 + 8 + grp*4);
  half8 M1   = ldfrag(pM + col*16 + grp*4), M2 = ldfrag(pM + col*16 + 8 + grp*4);
  half8 W1   = ldfrag(pW + col*16 + grp*4), W2 = ldfrag(pW + col*16 + 8 + grp*4);
  half8 D1   = ldfrag(pD + col*16 + grp*4), D2 = ldfrag(pD + col*16 + 8 + grp*4);
  half2v wv[8];
  #pragma unroll
  for (int j = 0; j < 8; j++) wv[j] = u2h(pwv[grp*8 + j]);

  f32x16 cb_bM = ldbias(bMf, grp);
  float ob0 = outb[0], ob1 = outb[1], ob2 = outb[2];
  f32x16 z16;
  #pragma unroll
  for (int i = 0; i < 16; i++) z16[i] = 0.f;

  // ---- pass-0 x loads issued at wave start ----
  float2 xr0[2][5], xr1[2][5];
  #pragma unroll
  for (int tt = 0; tt < 2; tt++){
    long long e = eW + 32*tt + col;
    if (e >= B) e = B - 1;
    const float2* xp = (const float2*)(x + e*10ll);
    xr0[tt][0]=xp[0]; xr0[tt][1]=xp[1]; xr0[tt][2]=xp[2];
    xr0[tt][3]=xp[3]; xr0[tt][4]=xp[4];
  }

  #pragma unroll
  for (int pp = 0; pp < 2; pp++){
    long long eB0 = eW + (long long)pp*64;

    // ---- phase 1: convert raw x -> packed B-frag (embb rides k=5 with 1.0) ----
    U4H8 xb0[2], xb1[2];
    #pragma unroll
    for (int tt = 0; tt < 2; tt++){
      const float2* q = (pp ? xr1 : xr0)[tt];
      float2 p0=q[0], p1=q[1], p2=q[2], p3=q[3], p4=q[4];
      xb0[tt].u[0] = g ? 0u : h2u(pkrtz(p0.x, p0.y));
      xb0[tt].u[1] = g ? 0u : h2u(pkrtz(p1.x, p1.y));
      xb0[tt].u[2] = g ? 0u : h2u(pkrtz(p2.x, 1.0f));
      xb0[tt].u[3] = 0u;
      xb1[tt].u[0] = g ? 0u : h2u(pkrtz(p2.y, p3.x));
      xb1[tt].u[1] = g ? 0u : h2u(pkrtz(p3.y, p4.x));
      xb1[tt].u[2] = g ? 0u : h2u(pkrtz(p4.y, 1.0f));
      xb1[tt].u[3] = 0u;
    }

    // ---- phase 2: embedding MFMAs (both tiles) + gelu ----
    f32x16 e0D[2], e1D[2];
    #pragma unroll
    for (int tt = 0; tt < 2; tt++){
      e0D[tt] = __builtin_amdgcn_mfma_f32_32x32x16_f16(embA, xb0[tt].h, z16, 0,0,0);
      e1D[tt] = __builtin_amdgcn_mfma_f32_32x32x16_f16(embA, xb1[tt].h, z16, 0,0,0);
    }
    unsigned int epk[2][8], dlpk[2][8];
    #pragma unroll
    for (int tt = 0; tt < 2; tt++){
      #pragma unroll
      for (int i = 0; i < 8; i++){
        half2v e0h = gelu_pk(pkrtz(e0D[tt][2*i], e0D[tt][2*i+1]));
        half2v e1h = gelu_pk(pkrtz(e1D[tt][2*i], e1D[tt][2*i+1]));
        epk[tt][i]  = h2u(e0h);
        dlpk[tt][i] = h2u(e1h - e0h);
      }
    }

    // ---- prefetch pass-1 x here: in flight across phases 3-7 of pass 0 ----
    if (pp == 0){
      #pragma unroll
      for (int tt = 0; tt < 2; tt++){
        long long e = eW + 64 + 32*tt + col;
        if (e >= B) e = B - 1;
        const float2* xp = (const float2*)(x + e*10ll);
        xr1[tt][0]=xp[0]; xr1[tt][1]=xp[1]; xr1[tt][2]=xp[2];
        xr1[tt][3]=xp[3]; xr1[tt][4]=xp[4];
      }
    }

    // ---- phase 3: score MFMAs + dots + cross-half reduce + softmax ----
    f32x16 gD[2];
    #pragma unroll
    for (int tt = 0; tt < 2; tt++){
      gD[tt] = __builtin_amdgcn_mfma_f32_32x32x16_f16(A1, h8of(dlpk[tt]), z16, 0,0,0);
      gD[tt] = __builtin_amdgcn_mfma_f32_32x32x16_f16(A2, h8of(dlpk[tt]+4), gD[tt], 0,0,0);
    }
    float a01[2], a11[2];
    #pragma unroll
    for (int tt = 0; tt < 2; tt++){
      float t0 = 0.f, t1 = 0.f, dw = 0.f;
      #pragma unroll
      for (int i = 0; i < 8; i++){
        half2v gp = pkrtz(gD[tt][2*i], gD[tt][2*i+1]);
        t0 = fdot2(u2h(epk[tt][i]),  gp, t0);
        t1 = fdot2(u2h(dlpk[tt][i]), gp, t1);
        dw = fdot2(wv[i], u2h(dlpk[tt][i]), dw);
      }
      t0 = red_sum32(t0);
      t1 = red_sum32(t1);
      dw = red_sum32(dw);
      a01[tt] = frcp(1.0f + __expf(-(t0      + dw)));
      a11[tt] = frcp(1.0f + __expf(-(t0 + t1 + dw)));
    }

    // ---- phase 4: c0/c1 in B-layout (packed) ----
    unsigned int c0pk[2][8], c1pk[2][8];
    #pragma unroll
    for (int tt = 0; tt < 2; tt++){
      _Float16 q01 = (_Float16)a01[tt], qda = (_Float16)(a11[tt] - a01[tt]);
      half2v s01 = {q01,q01}, sda = {qda,qda};
      #pragma unroll
      for (int j = 0; j < 8; j++){
        half2v c0 = u2h(dlpk[tt][j])*s01 + u2h(epk[tt][j]);
        half2v c1 = u2h(dlpk[tt][j])*sda + c0;
        c0pk[tt][j] = h2u(c0); c1pk[tt][j] = h2u(c1);
      }
    }

    // ---- phase 5: h1 MFMAs + tanh ----
    f32x16 h1D[2];
    #pragma unroll
    for (int tt = 0; tt < 2; tt++){
      h1D[tt] = __builtin_amdgcn_mfma_f32_32x32x16_f16(M1, h8of(c0pk[tt]), cb_bM, 0,0,0);
      h1D[tt] = __builtin_amdgcn_mfma_f32_32x32x16_f16(M2, h8of(c0pk[tt]+4), h1D[tt], 0,0,0);
    }
    unsigned int h1pk[2][8];
    #pragma unroll
    for (int tt = 0; tt < 2; tt++)
      #pragma unroll
      for (int i = 0; i < 8; i++)
        h1pk[tt][i] = h2u(tanh_pk(pkrtz(h1D[tt][2*i], h1D[tt][2*i+1])));

    // ---- phase 6: h2 MFMAs + tanh ----
    f32x16 h2D[2];
    #pragma unroll
    for (int tt = 0; tt < 2; tt++){
      h2D[tt] = __builtin_amdgcn_mfma_f32_32x32x16_f16(M1, h8of(c1pk[tt]), cb_bM, 0,0,0);
      h2D[tt] = __builtin_amdgcn_mfma_f32_32x32x16_f16(M2, h8of(c1pk[tt]+4), h2D[tt], 0,0,0);
      h2D[tt] = __builtin_amdgcn_mfma_f32_32x32x16_f16(W1, h8of(h1pk[tt]),   h2D[tt], 0,0,0);
      h2D[tt] = __builtin_amdgcn_mfma_f32_32x32x16_f16(W2, h8of(h1pk[tt]+4), h2D[tt], 0,0,0);
    }
    unsigned int h2pk[2][8];
    #pragma unroll
    for (int tt = 0; tt < 2; tt++)
      #pragma unroll
      for (int i = 0; i < 8; i++)
        h2pk[tt][i] = h2u(tanh_pk(pkrtz(h2D[tt][2*i], h2D[tt][2*i+1])));

    // ---- phase 7: decode MFMAs + packed epilogue + store ----
    f32x16 dvD[2];
    #pragma unroll
    for (int tt = 0; tt < 2; tt++){
      dvD[tt] = __builtin_amdgcn_mfma_f32_32x32x16_f16(D1, h8of(h2pk[tt]), z16, 0,0,0);
      dvD[tt] = __builtin_amdgcn_mfma_f32_32x32x16_f16(D2, h8of(h2pk[tt]+4), dvD[tt], 0,0,0);
    }
    #pragma unroll
    for (int tt = 0; tt < 2; tt++){
      float dv4 = upper_to_lower(dvD[tt][0]);   // grp1 reg0 = row 4
      half2v dp0 = pkrtz(dvD[tt][0], dvD[tt][1]) + u2h(pdb[0]);
      half2v dp1 = pkrtz(dvD[tt][2], dvD[tt][3]) + u2h(pdb[1]);
      half2v dp2 = pkrtz(dv4,        0.f       ) + u2h(pdb[2]);
      dp0 = gelu_pk(dp0); dp1 = gelu_pk(dp1); dp2 = gelu_pk(dp2);
      float y0 = fdot2(u2h(pout[0]), dp0, fdot2(u2h(pout[1]), dp1, fdot2(u2h(pout[2]), dp2, ob0)));
      float y1 = fdot2(u2h(pout[3]), dp0, fdot2(u2h(pout[4]), dp1, fdot2(u2h(pout[5]), dp2, ob1)));
      float y2 = fdot2(u2h(pout[6]), dp0, fdot2(u2h(pout[7]), dp1, fdot2(u2h(pout[8]), dp2, ob2)));
      long long e = eB0 + 32*tt + col;
      if (lane < 32 && e < B){
        float* yp = y + e*3ll;
        yp[0] = y0; yp[1] = y1; yp[2] = y2;
      }
    }
  }
}

extern "C" void kernel_launch(void* const* d_in, const int* in_sizes, int n_in,
                              void* d_out, int out_size, void* d_ws, size_t ws_size,
                              hipStream_t stream){
  const float* x    = (const float*)d_in[0];
  const float* embw = (const float*)d_in[1];
  const float* embb = (const float*)d_in[2];
  const float* inw  = (const float*)d_in[3];
  const float* inb  = (const float*)d_in[4];
  const float* opw  = (const float*)d_in[5];
  const float* opb  = (const float*)d_in[6];
  const float* wih  = (const float*)d_in[7];
  const float* bih  = (const float*)d_in[8];
  const float* whh  = (const float*)d_in[9];
  const float* bhh  = (const float*)d_in[10];
  const float* decw = (const float*)d_in[11];
  const float* decb = (const float*)d_in[12];
  const float* outw = (const float*)d_in[13];
  const float* outb = (const float*)d_in[14];
  float* y = (float*)d_out;
  unsigned int* wsu = (unsigned int*)d_ws;   // 2364 u32 = 9.5 KB

  long long B = in_sizes[0] / 10;            // [B,2,5]
  long long elems_per_block = (BT/64) * 128; // 512 (two 64-elem passes per wave)

  prep_kernel<<<1, 1024, 0, stream>>>(inw, inb, opw, opb, wih, bih, bhh,
                                      whh, decw, embw, embb, decb, outw, wsu);
  int grid = (int)((B + elems_per_block - 1)/elems_per_block);
  fused_kernel<<<grid, BT, 0, stream>>>(x, wsu, outb, y, B);
}

// Round 5
// 135.055 us; speedup vs baseline: 1.2344x; 1.2344x over previous
//
#include <hip/hip_runtime.h>
#include <math.h>

#define BT 256   // 4 waves; each wave = TWO 32-element tiles (64 elems) for ILP

typedef _Float16 half2v __attribute__((ext_vector_type(2)));
typedef __fp16   fp16x2 __attribute__((ext_vector_type(2)));
typedef _Float16 half8  __attribute__((ext_vector_type(8)));
typedef float    f32x16 __attribute__((ext_vector_type(16)));

union U4H8 { unsigned int u[4]; half8 h; };
struct __attribute__((packed)) F3 { float a, b, c; };

__device__ __forceinline__ half2v u2h(unsigned int u){
  union { unsigned int u; half2v h; } c; c.u = u; return c.h;
}
__device__ __forceinline__ unsigned int h2u(half2v h){
  union { unsigned int u; half2v h; } c; c.h = h; return c.u;
}
__device__ __forceinline__ half2v pkrtz(float a, float b){
  union { fp16x2 f; half2v h; } c;
  c.f = __builtin_amdgcn_cvt_pkrtz(a, b);
  return c.h;
}
__device__ __forceinline__ float fdot2(half2v a, half2v b, float c){
  return __builtin_amdgcn_fdot2(a, b, c, false);
}
__device__ __forceinline__ float frcp(float x){ return __builtin_amdgcn_rcpf(x); }

__device__ __forceinline__ unsigned int pk_rne(float a, float b){
  half2v h; h.x = (_Float16)a; h.y = (_Float16)b; return h2u(h);
}

// Cross-half (lane ^ 32) data movement on the VALU pipe (no DS / lgkm wait).
#if __has_builtin(__builtin_amdgcn_permlane32_swap)
#define HAVE_PLSWAP 1
#endif

// full sum of v[lane] + v[lane^32], valid in ALL lanes
__device__ __forceinline__ float red_sum32(float v){
#ifdef HAVE_PLSWAP
  union { float f; unsigned u; } c; c.f = v;
  auto r = __builtin_amdgcn_permlane32_swap(c.u, c.u, false, false);
  union { unsigned u; float f; } a, b; a.u = r[0]; b.u = r[1];
  return a.f + b.f;
#else
  return v + __shfl_xor(v, 32);
#endif
}
// lanes<32 receive v[l+32] (upper lanes get own value back)
__device__ __forceinline__ float upper_to_lower(float v){
#ifdef HAVE_PLSWAP
  union { float f; unsigned u; } c; c.f = v;
  auto r = __builtin_amdgcn_permlane32_swap(c.u, c.u, false, false);
  union { unsigned u; float f; } b; b.u = r[1];
  return b.f;
#else
  return __shfl_xor(v, 32);
#endif
}
// lanes>=32 receive v[l-32] (lower lanes get own value back)
__device__ __forceinline__ float lower_to_upper(float v){
#ifdef HAVE_PLSWAP
  union { float f; unsigned u; } c; c.f = v;
  auto r = __builtin_amdgcn_permlane32_swap(c.u, c.u, false, false);
  union { unsigned u; float f; } a; a.u = r[0];
  return a.f;
#else
  return __shfl_xor(v, 32);
#endif
}

// packed-f16 gelu: gelu(x) = x*S, S = clamp(0.5 + x*q(x^2), 0, 1);
// q deg-4 fit on t in [0,4]; |gelu err| <= 2.3e-4 on |x|<=2, correct asymptote beyond.
__device__ __forceinline__ half2v gelu_pk(half2v x){
  const _Float16 a0 = (_Float16)0.3989423f,  a1 = (_Float16)-0.0663157f,
                 a2 = (_Float16)0.0096298f,  a3 = (_Float16)-0.00095967f,
                 a4 = (_Float16)0.000048f,   hp = (_Float16)0.5f,
                 hn = (_Float16)-0.5f;
  const half2v A0={a0,a0}, A1={a1,a1}, A2={a2,a2}, A3={a3,a3}, A4={a4,a4};
  const half2v HP={hp,hp}, HN={hn,hn};
  half2v t = x*x;
  half2v q = A4*t + A3;
  q = q*t + A2;
  q = q*t + A1;
  q = q*t + A0;
  half2v u = x*q;
#if __has_builtin(__builtin_elementwise_min)
  u = __builtin_elementwise_max(u, HN);
  u = __builtin_elementwise_min(u, HP);
#else
  u.x = u.x > hp ? hp : (u.x < hn ? hn : u.x);
  u.y = u.y > hp ? hp : (u.y < hn ? hn : u.y);
#endif
  return x*(u + HP);
}

// packed-f16 tanh: clamp +-2, x*P(x^2), deg-5 fit (|err| ~5e-4 incl f16 rounding).
__device__ __forceinline__ half2v tanh_pk(half2v x){
  const _Float16 c0=(_Float16)0.999716f,  c1=(_Float16)-0.328107f,
                 c2=(_Float16)0.116352f,  c3=(_Float16)-0.031255f,
                 c4=(_Float16)0.005038f,  c5=(_Float16)-0.000348f,
                 tp=(_Float16)2.0f,       tn=(_Float16)-2.0f;
  const half2v C0={c0,c0},C1={c1,c1},C2={c2,c2},C3={c3,c3},C4={c4,c4},C5={c5,c5};
  const half2v TP={tp,tp}, TN={tn,tn};
#if __has_builtin(__builtin_elementwise_min)
  x = __builtin_elementwise_max(x, TN);
  x = __builtin_elementwise_min(x, TP);
#else
  x.x = x.x > tp ? tp : (x.x < tn ? tn : x.x);
  x.y = x.y > tp ? tp : (x.y < tn ? tn : x.y);
#endif
  half2v t = x*x;
  half2v p = C5*t + C4;
  p = p*t + C3;
  p = p*t + C2;
  p = p*t + C1;
  p = p*t + C0;
  return x*p;
}

// ---------------- ws layout (u32 words) ----------------
// sigma-permuted columns (pair j of a row = original cols c0,c0+1,
// c0 = 16*(j>>3) + 8*((j>>1)&1) + 4*((j>>2)&1) + 2*(j&1)) so the packed C/D
// pair array of the previous MFMA is directly the next B-fragment.
//  [0,512)     A_pk   : iss * Wq^T Wk            [32][16] pairs, perm cols
//  [512,1024)  M_pk   : M = W_ih*OP*WV           perm cols
//  [1024,1536) W_pk   : whh                      perm cols
//  [1536,2048) D_pk   : rows 0-4 = decw, else 0  perm cols
//  [2048,2304) emb_pk : [32][8] pairs; k<5 = embw, k=5 = embb (bias slot), else 0
//  [2304,2320) wv_pk  : iss * Wk^T bq, [grp][8] C/D row-pair order
//  [2320,2352) bM_f   : f32, bM = W_ih*(OP bv + opb) + b_ih + b_hh (natural)
//  [2352,2355) decb_pk: (b0,b1),(b2,b3),(b4,0)
//  [2355,2364) out_pk : row r: (w0,w1),(w2,w3),(w4,0)
__global__ void prep_kernel(const float* __restrict__ inw, const float* __restrict__ inb,
                            const float* __restrict__ opw, const float* __restrict__ opb,
                            const float* __restrict__ wih, const float* __restrict__ bih,
                            const float* __restrict__ bhh, const float* __restrict__ whh,
                            const float* __restrict__ decw, const float* __restrict__ embw,
                            const float* __restrict__ embb,
                            const float* __restrict__ decb, const float* __restrict__ outw,
                            unsigned int* __restrict__ wsu){
  __shared__ float sQ[1024], sK[1024], sV[1024], sOP[1024], sWI[1024];
  __shared__ float sA[1024], sP[1024], sM[1024], sT[32], sWV[32];
  const float ISS = 0.17677669529663689f;   // 1/sqrt(32)
  int t = threadIdx.x;
  sQ[t]  = inw[t];
  sK[t]  = inw[1024 + t];
  sV[t]  = inw[2048 + t];
  sOP[t] = opw[t];
  sWI[t] = wih[t];
  __syncthreads();
  int tx = t & 31, ty = t >> 5;
  float accA = 0.f, accP = 0.f;
  #pragma unroll
  for (int m = 0; m < 32; m++){
    accA += sQ[m*32 + ty] * sK[m*32 + tx];    // Wq[m,ty]*Wk[m,tx]
    accP += sOP[ty*32 + m] * sV[m*32 + tx];   // OP[ty,m]*WV[m,tx]
  }
  sA[ty*32 + tx] = accA;
  sP[ty*32 + tx] = accP;
  if (ty == 0){
    float aw = 0.f;
    #pragma unroll
    for (int m = 0; m < 32; m++) aw += inb[m] * sK[m*32 + tx];   // bq[m]*Wk[m,tx]
    sWV[tx] = aw;
  }
  if (ty == 1){
    float at = opb[tx];
    #pragma unroll
    for (int m = 0; m < 32; m++) at += sOP[tx*32 + m] * inb[64 + m];  // OP[tx,m]*bv[m]
    sT[tx] = at;
  }
  __syncthreads();
  float accM = 0.f;
  #pragma unroll
  for (int m = 0; m < 32; m++) accM += sWI[ty*32 + m] * sP[m*32 + tx];
  sM[ty*32 + tx] = accM;
  if (ty == 2){
    float ab = bih[tx] + bhh[tx];
    #pragma unroll
    for (int m = 0; m < 32; m++) ab += sWI[tx*32 + m] * sT[m];
    ((float*)wsu)[2320 + tx] = ab;
  }
  __syncthreads();
  if (t < 512){
    int r = t >> 4, j = t & 15;
    int c0 = 16*(j>>3) + 8*((j>>1)&1) + 4*((j>>2)&1) + 2*(j&1);   // sigma-perm
    wsu[t]        = pk_rne(ISS*sA[r*32+c0], ISS*sA[r*32+c0+1]);
    wsu[512 + t]  = pk_rne(sM[r*32+c0],  sM[r*32+c0+1]);
    wsu[1024 + t] = pk_rne(whh[r*32+c0], whh[r*32+c0+1]);
    wsu[1536 + t] = (r < 5) ? pk_rne(decw[r*32+c0], decw[r*32+c0+1]) : 0u;
  } else if (t < 768){                     // emb_pk: [32][8] pairs; k5 = embb
    int q = t - 512, j2 = q >> 3, cc = (q & 7)*2;
    float a = (cc   < 5) ? embw[j2*5+cc]   : 0.f;
    float b = (cc+1 < 5) ? embw[j2*5+cc+1] : ((cc+1 == 5) ? embb[j2] : 0.f);
    wsu[2048 + q] = pk_rne(a, b);
  } else if (t < 784){                     // wv_pk in C/D row-pair order, iss-scaled
    int q = t - 768, gg = q >> 3, j = q & 7;
    int r0 = 2*(j&1) + 8*(j>>1) + 4*gg;
    wsu[2304 + q] = pk_rne(ISS*sWV[r0], ISS*sWV[r0+1]);
  } else if (t < 787){                     // decb_pk
    int i = t - 784, c = 2*i;
    float a = decb[c];
    float b = (c+1 < 5) ? decb[c+1] : 0.f;
    wsu[2352 + i] = pk_rne(a, b);
  } else if (t < 796){                     // out_pk: 3 rows x 3 pairs
    int q = t - 787;
    int r = (q >= 6) ? 2 : ((q >= 3) ? 1 : 0);
    int p = q - r*3, c = 2*p;
    float a = outw[r*5 + c];
    float b = (c+1 < 5) ? outw[r*5 + c + 1] : 0.f;
    wsu[2355 + q] = pk_rne(a, b);
  }
}

__device__ __forceinline__ half8 ldfrag(const unsigned int* __restrict__ p){
  U4H8 t; t.u[0]=p[0]; t.u[1]=p[1]; t.u[2]=p[2]; t.u[3]=p[3]; return t.h;
}
__device__ __forceinline__ half8 h8of(const unsigned int* q){
  U4H8 t; t.u[0]=q[0]; t.u[1]=q[1]; t.u[2]=q[2]; t.u[3]=q[3]; return t.h;
}

// 16 f32 bias values for this lane's C-frag rows via 4x float4
__device__ __forceinline__ f32x16 ldbias(const float* __restrict__ p, int grp){
  const float4* b = (const float4*)(p + 4*grp);
  float4 q0 = b[0], q1 = b[2], q2 = b[4], q3 = b[6];
  f32x16 c;
  c[0]=q0.x; c[1]=q0.y; c[2]=q0.z; c[3]=q0.w;
  c[4]=q1.x; c[5]=q1.y; c[6]=q1.z; c[7]=q1.w;
  c[8]=q2.x; c[9]=q2.y; c[10]=q2.z; c[11]=q2.w;
  c[12]=q3.x; c[13]=q3.y; c[14]=q3.z; c[15]=q3.w;
  return c;
}

__global__ __launch_bounds__(BT, 4) void fused_kernel(
    const float* __restrict__ x,
    const unsigned int* __restrict__ wsu,
    const float* __restrict__ outb,
    float* __restrict__ y, long long B)
{
  int tid  = threadIdx.x;
  int lane = tid & 63;
  int col  = lane & 31;
  bool g   = (lane >> 5) != 0;
  int grp  = g ? 1 : 0;

  unsigned B32  = (unsigned)B;
  unsigned Bm1  = B32 - 1u;
  unsigned eBase = ((unsigned)blockIdx.x*(BT/64) + (unsigned)(tid>>6)) * 64u;
  if (eBase >= B32) return;
  bool full = (eBase + 64u <= B32);       // wave-uniform

  const unsigned int* pA = wsu;
  const unsigned int* pM = wsu + 512;
  const unsigned int* pW = wsu + 1024;
  const unsigned int* pD = wsu + 1536;
  const unsigned int* pE = wsu + 2048;
  const unsigned int* pwv = wsu + 2304;
  const float* bMf = (const float*)(wsu + 2320);
  const unsigned int* pdb  = wsu + 2352;
  const unsigned int* pout = wsu + 2355;

  half8 embA = ldfrag(pE + col*8  + grp*4);
  half8 A1   = ldfrag(pA + col*16 + grp*4), A2 = ldfrag(pA + col*16 + 8 + grp*4);
  half8 M1   = ldfrag(pM + col*16 + grp*4), M2 = ldfrag(pM + col*16 + 8 + grp*4);
  half8 W1   = ldfrag(pW + col*16 + grp*4), W2 = ldfrag(pW + col*16 + 8 + grp*4);
  half8 D1   = ldfrag(pD + col*16 + grp*4), D2 = ldfrag(pD + col*16 + 8 + grp*4);
  half2v wv[8];
  #pragma unroll
  for (int j = 0; j < 8; j++) wv[j] = u2h(pwv[grp*8 + j]);
  unsigned db01u = pdb[0], db23u = pdb[1], db4u = pdb[2];

  f32x16 cb_bM = ldbias(bMf, grp);
  float ob0 = outb[0], ob1 = outb[1], ob2 = outb[2];
  f32x16 z16;
  #pragma unroll
  for (int i = 0; i < 16; i++) z16[i] = 0.f;

  // ---- phase 1: x loads (half-exec) + packed conversion (32-bit addressing) ----
  U4H8 xb0[2], xb1[2];
  #pragma unroll
  for (int tt = 0; tt < 2; tt++){
    xb0[tt].u[0]=0u; xb0[tt].u[1]=0u; xb0[tt].u[2]=0u; xb0[tt].u[3]=0u;
    xb1[tt].u[0]=0u; xb1[tt].u[1]=0u; xb1[tt].u[2]=0u; xb1[tt].u[3]=0u;
  }
  if (!g){
    #pragma unroll
    for (int tt = 0; tt < 2; tt++){
      unsigned e = eBase + 32u*tt + (unsigned)col;
      e = e < Bm1 ? e : Bm1;                       // v_min_u32
      const float2* xp = (const float2*)((const char*)x + (size_t)(e*40u));
      float2 p0 = xp[0], p1 = xp[1], p2 = xp[2], p3 = xp[3], p4 = xp[4];
      xb0[tt].u[0] = h2u(pkrtz(p0.x, p0.y));
      xb0[tt].u[1] = h2u(pkrtz(p1.x, p1.y));
      xb0[tt].u[2] = h2u(pkrtz(p2.x, 1.0f));
      xb1[tt].u[0] = h2u(pkrtz(p2.y, p3.x));
      xb1[tt].u[1] = h2u(pkrtz(p3.y, p4.x));
      xb1[tt].u[2] = h2u(pkrtz(p4.y, 1.0f));
    }
  }

  // ---- phase 2: embedding MFMAs (both tiles) + gelu ----
  f32x16 e0D[2], e1D[2];
  #pragma unroll
  for (int tt = 0; tt < 2; tt++){
    e0D[tt] = __builtin_amdgcn_mfma_f32_32x32x16_f16(embA, xb0[tt].h, z16, 0,0,0);
    e1D[tt] = __builtin_amdgcn_mfma_f32_32x32x16_f16(embA, xb1[tt].h, z16, 0,0,0);
  }
  unsigned int epk[2][8], dlpk[2][8];
  #pragma unroll
  for (int tt = 0; tt < 2; tt++){
    #pragma unroll
    for (int i = 0; i < 8; i++){
      half2v e0h = gelu_pk(pkrtz(e0D[tt][2*i], e0D[tt][2*i+1]));
      half2v e1h = gelu_pk(pkrtz(e1D[tt][2*i], e1D[tt][2*i+1]));
      epk[tt][i]  = h2u(e0h);
      dlpk[tt][i] = h2u(e1h - e0h);
    }
  }

  // ---- phase 3: score MFMAs + dots + cross-half reduce + softmax ----
  f32x16 gD[2];
  #pragma unroll
  for (int tt = 0; tt < 2; tt++){
    gD[tt] = __builtin_amdgcn_mfma_f32_32x32x16_f16(A1, h8of(dlpk[tt]), z16, 0,0,0);
    gD[tt] = __builtin_amdgcn_mfma_f32_32x32x16_f16(A2, h8of(dlpk[tt]+4), gD[tt], 0,0,0);
  }
  float a01[2], a11[2];
  #pragma unroll
  for (int tt = 0; tt < 2; tt++){
    float t0 = 0.f, t1 = 0.f, dw = 0.f;
    #pragma unroll
    for (int i = 0; i < 8; i++){
      half2v gp = pkrtz(gD[tt][2*i], gD[tt][2*i+1]);
      t0 = fdot2(u2h(epk[tt][i]),  gp, t0);
      t1 = fdot2(u2h(dlpk[tt][i]), gp, t1);
      dw = fdot2(wv[i], u2h(dlpk[tt][i]), dw);
    }
    float s0 = red_sum32(t0 + dw);          // pre-add dw: 2 reductions not 3
    t1 = red_sum32(t1);
    a01[tt] = frcp(1.0f + __expf(-s0));
    a11[tt] = frcp(1.0f + __expf(-(s0 + t1)));
  }

  // ---- phase 4: c0/c1 in B-layout (packed) ----
  unsigned int c0pk[2][8], c1pk[2][8];
  #pragma unroll
  for (int tt = 0; tt < 2; tt++){
    _Float16 q01 = (_Float16)a01[tt], qda = (_Float16)(a11[tt] - a01[tt]);
    half2v s01 = {q01,q01}, sda = {qda,qda};
    #pragma unroll
    for (int j = 0; j < 8; j++){
      half2v c0 = u2h(dlpk[tt][j])*s01 + u2h(epk[tt][j]);
      half2v c1 = u2h(dlpk[tt][j])*sda + c0;
      c0pk[tt][j] = h2u(c0); c1pk[tt][j] = h2u(c1);
    }
  }

  // ---- phase 5: h1 MFMAs + tanh ----
  f32x16 h1D[2];
  #pragma unroll
  for (int tt = 0; tt < 2; tt++){
    h1D[tt] = __builtin_amdgcn_mfma_f32_32x32x16_f16(M1, h8of(c0pk[tt]), cb_bM, 0,0,0);
    h1D[tt] = __builtin_amdgcn_mfma_f32_32x32x16_f16(M2, h8of(c0pk[tt]+4), h1D[tt], 0,0,0);
  }
  unsigned int h1pk[2][8];
  #pragma unroll
  for (int tt = 0; tt < 2; tt++)
    #pragma unroll
    for (int i = 0; i < 8; i++)
      h1pk[tt][i] = h2u(tanh_pk(pkrtz(h1D[tt][2*i], h1D[tt][2*i+1])));

  // ---- phase 6: h2 MFMAs + tanh ----
  f32x16 h2D[2];
  #pragma unroll
  for (int tt = 0; tt < 2; tt++){
    h2D[tt] = __builtin_amdgcn_mfma_f32_32x32x16_f16(M1, h8of(c1pk[tt]), cb_bM, 0,0,0);
    h2D[tt] = __builtin_amdgcn_mfma_f32_32x32x16_f16(M2, h8of(c1pk[tt]+4), h2D[tt], 0,0,0);
    h2D[tt] = __builtin_amdgcn_mfma_f32_32x32x16_f16(W1, h8of(h1pk[tt]),   h2D[tt], 0,0,0);
    h2D[tt] = __builtin_amdgcn_mfma_f32_32x32x16_f16(W2, h8of(h1pk[tt]+4), h2D[tt], 0,0,0);
  }
  unsigned int h2pk[2][8];
  #pragma unroll
  for (int tt = 0; tt < 2; tt++)
    #pragma unroll
    for (int i = 0; i < 8; i++)
      h2pk[tt][i] = h2u(tanh_pk(pkrtz(h2D[tt][2*i], h2D[tt][2*i+1])));

  // ---- phase 7: decode MFMAs (bias in C) + lane-split epilogue + store ----
  {
    half2v b01 = u2h(db01u), b23 = u2h(db23u), b4x = u2h(db4u);
    float db0 = (float)b01.x, db1 = (float)b01.y;
    float db2 = (float)b23.x, db3 = (float)b23.y;
    float db4 = (float)b4x.x;
    f32x16 cdec;
    #pragma unroll
    for (int i = 0; i < 16; i++) cdec[i] = 0.f;
    cdec[0] = g ? db4 : db0;
    cdec[1] = g ? 0.f : db1;
    cdec[2] = g ? 0.f : db2;
    cdec[3] = g ? 0.f : db3;

    f32x16 dvD[2];
    #pragma unroll
    for (int tt = 0; tt < 2; tt++){
      dvD[tt] = __builtin_amdgcn_mfma_f32_32x32x16_f16(D1, h8of(h2pk[tt]), cdec, 0,0,0);
      dvD[tt] = __builtin_amdgcn_mfma_f32_32x32x16_f16(D2, h8of(h2pk[tt]+4), dvD[tt], 0,0,0);
    }
    // tile0 rows 0-3 live in lanes<32 regs 0-3, tile0 row4 in lanes>=32 reg0 (biases included).
    float d4l = upper_to_lower(dvD[0][0]);   // lanes<32: tile0 row4
    float q0  = lower_to_upper(dvD[1][0]);   // lanes>=32: tile1 rows0-3
    float q1  = lower_to_upper(dvD[1][1]);
    float q2  = lower_to_upper(dvD[1][2]);
    float q3  = lower_to_upper(dvD[1][3]);
    float d0 = g ? q0 : dvD[0][0];
    float d1 = g ? q1 : dvD[0][1];
    float d2 = g ? q2 : dvD[0][2];
    float d3 = g ? q3 : dvD[0][3];
    float d4 = g ? dvD[1][0] : d4l;          // upper's own reg0 = tile1 row4
    half2v dp0 = gelu_pk(pkrtz(d0, d1));
    half2v dp1 = gelu_pk(pkrtz(d2, d3));
    half2v dp2 = gelu_pk(pkrtz(d4, 0.f));
    float y0 = fdot2(u2h(pout[0]), dp0, fdot2(u2h(pout[1]), dp1, fdot2(u2h(pout[2]), dp2, ob0)));
    float y1 = fdot2(u2h(pout[3]), dp0, fdot2(u2h(pout[4]), dp1, fdot2(u2h(pout[5]), dp2, ob1)));
    float y2 = fdot2(u2h(pout[6]), dp0, fdot2(u2h(pout[7]), dp1, fdot2(u2h(pout[8]), dp2, ob2)));
    unsigned e = eBase + (unsigned)lane;      // lane half == tile index
    F3 out; out.a = y0; out.b = y1; out.c = y2;
    F3* yp = (F3*)((char*)y + (size_t)(e*12u));
    if (full){
      *yp = out;
    } else if (e < B32){
      *yp = out;
    }
  }
}

extern "C" void kernel_launch(void* const* d_in, const int* in_sizes, int n_in,
                              void* d_out, int out_size, void* d_ws, size_t ws_size,
                              hipStream_t stream){
  const float* x    = (const float*)d_in[0];
  const float* embw = (const float*)d_in[1];
  const float* embb = (const float*)d_in[2];
  const float* inw  = (const float*)d_in[3];
  const float* inb  = (const float*)d_in[4];
  const float* opw  = (const float*)d_in[5];
  const float* opb  = (const float*)d_in[6];
  const float* wih  = (const float*)d_in[7];
  const float* bih  = (const float*)d_in[8];
  const float* whh  = (const float*)d_in[9];
  const float* bhh  = (const float*)d_in[10];
  const float* decw = (const float*)d_in[11];
  const float* decb = (const float*)d_in[12];
  const float* outw = (const float*)d_in[13];
  const float* outb = (const float*)d_in[14];
  float* y = (float*)d_out;
  unsigned int* wsu = (unsigned int*)d_ws;   // 2364 u32 = 9.5 KB

  long long B = in_sizes[0] / 10;            // [B,2,5]
  long long elems_per_block = (BT/64) * 64;  // 256

  prep_kernel<<<1, 1024, 0, stream>>>(inw, inb, opw, opb, wih, bih, bhh,
                                      whh, decw, embw, embb, decb, outw, wsu);
  int grid = (int)((B + elems_per_block - 1)/elems_per_block);
  fused_kernel<<<grid, BT, 0, stream>>>(x, wsu, outb, y, B);
}